// Round 7
// baseline (56.041 us; speedup 1.0000x reference)
//
#include <hip/hip_runtime.h>
#include <hip/hip_bf16.h>

typedef float f32x4 __attribute__((ext_vector_type(4)));
typedef __bf16 bf16x8 __attribute__((ext_vector_type(8)));

union Frag { unsigned short h[8]; unsigned int u[4]; uint4 u4; bf16x8 b; };

__device__ __forceinline__ unsigned short f2bs(float f){
  __hip_bfloat16 v = __float2bfloat16(f);
  return __builtin_bit_cast(unsigned short, v);
}
// 1-instruction bf16 pair pack (RNE)
__device__ __forceinline__ unsigned int pk2(float a, float b){
  unsigned int r;
  asm("v_cvt_pk_bf16_f32 %0, %1, %2" : "=v"(r) : "v"(a), "v"(b));
  return r;
}
__device__ __forceinline__ Frag packF(f32x4 a, f32x4 b){
  Frag f;
  f.u[0] = pk2(a[0], a[1]); f.u[1] = pk2(a[2], a[3]);
  f.u[2] = pk2(b[0], b[1]); f.u[3] = pk2(b[2], b[3]);
  return f;
}
__device__ __forceinline__ f32x4 relu4(f32x4 v){
  f32x4 r;
  #pragma unroll
  for (int j = 0; j < 4; ++j) r[j] = fmaxf(v[j], 0.f);
  return r;
}
__device__ __forceinline__ float sigmoid_fast(float x){
  return __builtin_amdgcn_rcpf(1.f + __expf(-x));
}

// ---------------------------------------------------------------------------
// Prep: weight matrices -> MFMA A-frag order bf16 (ws[0..4095] uint4), plus
// r2e's 5 rows pre-packed as B-frag pairs (ws[4096..4735]).
// A-frag element (h,j): W[16*m + (lane&15)][32*s + 16*h + 4*(lane>>4) + j]
// ---------------------------------------------------------------------------
__global__ void prep_weights(const float* __restrict__ w1, const float* __restrict__ w2,
                             const float* __restrict__ mu, const float* __restrict__ a1,
                             const float* __restrict__ a2, const float* __restrict__ r2e,
                             uint4* __restrict__ ws){
  const int f = blockIdx.x;
  const int l = threadIdx.x;
  Frag fr;
  if (f < 64){
    const float* W; int m, s, K;
    if (f < 16)      { W = w1; m = f >> 2;        s = f & 3;        K = 128; }
    else if (f < 24) { W = w2; m = (f - 16) >> 1; s = (f - 16) & 1; K = 64;  }
    else if (f < 40) { W = mu; m = (f - 24) >> 2; s = (f - 24) & 3; K = 128; }
    else if (f < 56) { W = a1; m = (f - 40) >> 2; s = (f - 40) & 3; K = 128; }
    else             { W = a2; m = (f - 56) >> 1; s = (f - 56) & 1; K = 64;  }
    const int row = 16 * m + (l & 15);
    const int k0  = 32 * s + 4 * (l >> 4);
    #pragma unroll
    for (int h = 0; h < 2; ++h)
      #pragma unroll
      for (int j = 0; j < 4; ++j)
        fr.h[4*h + j] = f2bs(W[row * K + k0 + 16*h + j]);
    ws[f * 64 + l] = fr.u4;
  } else {
    const int f2 = f - 64;            // 0..9
    const int R = f2 >> 1, sp = f2 & 1;
    const int g = (l >> 4) & 3;
    #pragma unroll
    for (int h = 0; h < 2; ++h)
      #pragma unroll
      for (int j = 0; j < 4; ++j)
        fr.h[4*h + j] = f2bs(r2e[R * 64 + sp * 32 + 16*h + 4*g + j]);
    ws[4096 + f2 * 64 + l] = fr.u4;
  }
}

// ---------------------------------------------------------------------------
// Main: grid 512 x 512thr (8 waves). Each block owns 4 nodes; each node is
// split across 2 waves (half 0: tile-pairs 0..3, half 1: pairs 4..6), each
// wave running the dual-chunk (2x ILP) pipeline from round 6. Rationale:
// LDS (77KB weight table) caps blocks/CU at 2 regardless of block size, so
// doubling threads/block doubles waves/CU: 8 -> 16 (4 waves/SIMD).
// Max-free softmax makes the 2-way merge a pure sum in LDS.
// Per-iteration es-reduce deferred to the finale (per-lane accumulate).
// NOTE: no min-waves launch_bounds arg (round 3: cap => ~1GB scratch spill).
// LDS (79392 B): [0,65536) uint4 wlds[4096]; [65536,67072) float bias[384];
//   [67072,77312) uint4 rlds[640]; [77312,79360) float mAcc[4][2][64];
//   [79360,79392) float mSw[4][2]
// ---------------------------------------------------------------------------
__global__ __launch_bounds__(512)
void uv_agg_main(const int* __restrict__ nodes, const int* __restrict__ huv,
                 const int* __restrict__ hr, const float* __restrict__ u2e,
                 const float* __restrict__ v2e,
                 const float* __restrict__ b1g, const float* __restrict__ b2g,
                 const float* __restrict__ bmg, const float* __restrict__ ba1g,
                 const float* __restrict__ ba2g, const float* __restrict__ a3g,
                 const uint4* __restrict__ wsfrag, float* __restrict__ out){
  extern __shared__ unsigned char smem[];
  uint4* wlds = (uint4*)smem;
  float* bias = (float*)(smem + 65536);
  uint4* rlds = (uint4*)(smem + 67072);
  float* mAcc = (float*)(smem + 77312);   // [ns][half][64]
  float* mSw  = (float*)(smem + 79360);   // [ns][half]

  const int tid  = threadIdx.x;
  const int lane = tid & 63;
  const int wave = tid >> 6;     // 0..7
  const int ns   = wave & 3;     // node sub-index in block
  const int half = wave >> 2;    // 0: pairs 0..3, 1: pairs 4..6
  const int g    = lane >> 4;
  const int r16  = lane & 15;
  const int n    = blockIdx.x * 4 + ns;

  // stage weight frag table + r2e frags + biases into LDS (512 threads)
  #pragma unroll
  for (int k = 0; k < 8; ++k) wlds[k * 512 + tid] = wsfrag[k * 512 + tid];
  for (int i = tid; i < 640; i += 512)  rlds[i] = wsfrag[4096 + i];
  if (tid < 384){
    const int w = tid >> 6, d = tid & 63;
    const float* src = (w==0)?b1g:(w==1)?b2g:(w==2)?bmg:(w==3)?ba1g:(w==4)?ba2g:a3g;
    bias[tid] = src[d];
  }
  __syncthreads();

  const uint4* wl = wlds + lane;
  const f32x4* bl = (const f32x4*)bias + g;
  const unsigned char* rbase = (const unsigned char*)rlds + lane * 16;
  const int* hu  = huv + n * 200;
  const int* hrw = hr  + n * 200;

  // per-node q = v2e[nodes[n]]
  const int item = nodes[n];
  f32x4 qv[4];
  #pragma unroll
  for (int m = 0; m < 4; ++m)
    qv[m] = *(const f32x4*)(v2e + (size_t)item * 64 + 16*m + 4*g);
  Frag qf[2];
  qf[0] = packF(qv[0], qv[1]); qf[1] = packF(qv[2], qv[3]);

  float swl = 0.f;                 // per-lane exp-sum (reduced in finale)
  f32x4 accw[4];
  #pragma unroll
  for (int m = 0; m < 4; ++m) accw[m] = (f32x4)(0.f);

  const int it0 = half ? 4 : 0;
  const int itE = half ? 7 : 4;

  // initial gather: pair it0 (tiles 2it0, 2it0+1)
  int irA, irB;
  f32x4 urA[4], urB[4];
  {
    const int kA = min(32*it0 + r16, 199);
    const int kB = min(32*it0 + 16 + r16, 199);
    const int iuA = hu[kA]; irA = hrw[kA];
    const int iuB = hu[kB]; irB = hrw[kB];
    const f32x4* ua = (const f32x4*)(u2e + (size_t)iuA * 64);
    const f32x4* ub = (const f32x4*)(u2e + (size_t)iuB * 64);
    #pragma unroll
    for (int s = 0; s < 4; ++s){ urA[s] = ua[4*s + g]; urB[s] = ub[4*s + g]; }
  }

  for (int it = it0; it < itE; ++it){
    Frag b0A[2], b0B[2];
    b0A[0] = packF(urA[0], urA[1]); b0A[1] = packF(urA[2], urA[3]);
    b0B[0] = packF(urB[0], urB[1]); b0B[1] = packF(urB[2], urB[3]);
    const int ircA = irA, ircB = irB;
    const bool vA = (32*it + r16) < 200;
    const bool vB = (32*it + 16 + r16) < 200;

    // prefetch next pair (independent of this iteration's chains)
    if (it + 1 < itE){
      const int base = 32*it + 32;
      const int kA = min(base + r16, 199);
      const int kB = min(base + 16 + r16, 199);
      const int iuA = hu[kA]; irA = hrw[kA];
      const int iuB = hu[kB]; irB = hrw[kB];
      const f32x4* ua = (const f32x4*)(u2e + (size_t)iuA * 64);
      const f32x4* ub = (const f32x4*)(u2e + (size_t)iuB * 64);
      #pragma unroll
      for (int s = 0; s < 4; ++s){ urA[s] = ua[4*s + g]; urB[s] = ub[4*s + g]; }
    }

    // S1: X = relu(W1 @ concat(e_uv, e_r) + b1)   [two chunks interleaved]
    f32x4 XA[4], XB[4];
    #pragma unroll
    for (int m = 0; m < 4; ++m){
      const f32x4 bi = bl[0*16 + 4*m];
      f32x4 aA = bi, aB = bi;
      #pragma unroll
      for (int s = 0; s < 4; ++s){
        Frag w; w.u4 = wl[(m*4 + s) * 64];
        Frag eA, eB;
        if (s < 2){ eA = b0A[s]; eB = b0B[s]; }
        else {
          eA.u4 = *(const uint4*)(rbase + (size_t)(ircA*2 + (s-2)) * 1024);
          eB.u4 = *(const uint4*)(rbase + (size_t)(ircB*2 + (s-2)) * 1024);
        }
        aA = __builtin_amdgcn_mfma_f32_16x16x32_bf16(w.b, eA.b, aA, 0, 0, 0);
        aB = __builtin_amdgcn_mfma_f32_16x16x32_bf16(w.b, eB.b, aB, 0, 0, 0);
      }
      XA[m] = relu4(aA); XB[m] = relu4(aB);
    }
    Frag bxA[2], bxB[2];
    bxA[0] = packF(XA[0], XA[1]); bxA[1] = packF(XA[2], XA[3]);
    bxB[0] = packF(XB[0], XB[1]); bxB[1] = packF(XB[2], XB[3]);

    // S2: O = relu(W2 @ X + b2)
    f32x4 OA[4], OB[4];
    #pragma unroll
    for (int m = 0; m < 4; ++m){
      const f32x4 bi = bl[1*16 + 4*m];
      f32x4 aA = bi, aB = bi;
      #pragma unroll
      for (int s = 0; s < 2; ++s){
        Frag w; w.u4 = wl[(16 + m*2 + s) * 64];
        aA = __builtin_amdgcn_mfma_f32_16x16x32_bf16(w.b, bxA[s].b, aA, 0, 0, 0);
        aB = __builtin_amdgcn_mfma_f32_16x16x32_bf16(w.b, bxB[s].b, aB, 0, 0, 0);
      }
      OA[m] = relu4(aA); OB[m] = relu4(aB);
    }
    Frag boA[2], boB[2];
    boA[0] = packF(OA[0], OA[1]); boA[1] = packF(OA[2], OA[3]);
    boB[0] = packF(OB[0], OB[1]); boB[1] = packF(OB[2], OB[3]);

    // S3: gate = sigmoid(MU @ concat(O,q) + mu_b); OG = q + gate*(O-q)
    f32x4 OGA[4], OGB[4];
    #pragma unroll
    for (int m = 0; m < 4; ++m){
      const f32x4 bi = bl[2*16 + 4*m];
      f32x4 aA = bi, aB = bi;
      #pragma unroll
      for (int s = 0; s < 4; ++s){
        Frag w; w.u4 = wl[(24 + m*4 + s) * 64];
        const bf16x8 eA = (s < 2) ? boA[s].b : qf[s-2].b;
        const bf16x8 eB = (s < 2) ? boB[s].b : qf[s-2].b;
        aA = __builtin_amdgcn_mfma_f32_16x16x32_bf16(w.b, eA, aA, 0, 0, 0);
        aB = __builtin_amdgcn_mfma_f32_16x16x32_bf16(w.b, eB, aB, 0, 0, 0);
      }
      #pragma unroll
      for (int j = 0; j < 4; ++j){
        const float gA = sigmoid_fast(aA[j]);
        const float gB = sigmoid_fast(aB[j]);
        OGA[m][j] = fmaf(gA, OA[m][j] - qv[m][j], qv[m][j]);
        OGB[m][j] = fmaf(gB, OB[m][j] - qv[m][j], qv[m][j]);
      }
    }
    Frag bgA[2], bgB[2];
    bgA[0] = packF(OGA[0], OGA[1]); bgA[1] = packF(OGA[2], OGA[3]);
    bgB[0] = packF(OGB[0], OGB[1]); bgB[1] = packF(OGB[2], OGB[3]);

    // S4: A1 = relu(ATT1 @ concat(OG,q) + att1_b)
    f32x4 A1A[4], A1B[4];
    #pragma unroll
    for (int m = 0; m < 4; ++m){
      const f32x4 bi = bl[3*16 + 4*m];
      f32x4 aA = bi, aB = bi;
      #pragma unroll
      for (int s = 0; s < 4; ++s){
        Frag w; w.u4 = wl[(40 + m*4 + s) * 64];
        const bf16x8 eA = (s < 2) ? bgA[s].b : qf[s-2].b;
        const bf16x8 eB = (s < 2) ? bgB[s].b : qf[s-2].b;
        aA = __builtin_amdgcn_mfma_f32_16x16x32_bf16(w.b, eA, aA, 0, 0, 0);
        aB = __builtin_amdgcn_mfma_f32_16x16x32_bf16(w.b, eB, aB, 0, 0, 0);
      }
      A1A[m] = relu4(aA); A1B[m] = relu4(aB);
    }
    Frag b4A[2], b4B[2];
    b4A[0] = packF(A1A[0], A1A[1]); b4A[1] = packF(A1A[2], A1A[3]);
    b4B[0] = packF(A1B[0], A1B[1]); b4B[1] = packF(A1B[2], A1B[3]);

    // S5: A2 = relu(ATT2 @ A1 + att2_b); logit = dot(att3_w, A2_row)
    float pA = 0.f, pB = 0.f;
    #pragma unroll
    for (int m = 0; m < 4; ++m){
      const f32x4 bi = bl[4*16 + 4*m];
      f32x4 aA = bi, aB = bi;
      #pragma unroll
      for (int s = 0; s < 2; ++s){
        Frag w; w.u4 = wl[(56 + m*2 + s) * 64];
        aA = __builtin_amdgcn_mfma_f32_16x16x32_bf16(w.b, b4A[s].b, aA, 0, 0, 0);
        aB = __builtin_amdgcn_mfma_f32_16x16x32_bf16(w.b, b4B[s].b, aB, 0, 0, 0);
      }
      aA = relu4(aA); aB = relu4(aB);
      const f32x4 a3m = bl[5*16 + 4*m];
      #pragma unroll
      for (int j = 0; j < 4; ++j){
        pA = fmaf(a3m[j], aA[j], pA);
        pB = fmaf(a3m[j], aB[j], pB);
      }
    }
    pA += __shfl_xor(pA, 16); pA += __shfl_xor(pA, 32);
    pB += __shfl_xor(pB, 16); pB += __shfl_xor(pB, 32);

    // max-free online softmax (logits O(1e-2); guard at 60); es-reduce deferred
    const float eA = vA ? __expf(fminf(pA, 60.f)) : 0.f;
    const float eB = vB ? __expf(fminf(pB, 60.f)) : 0.f;
    swl += eA + eB;
    #pragma unroll
    for (int m = 0; m < 4; ++m)
      #pragma unroll
      for (int j = 0; j < 4; ++j)
        accw[m][j] = fmaf(eA, OGA[m][j], fmaf(eB, OGB[m][j], accw[m][j]));
  }

  // finale: reduce over the 16 row-lanes (accw and swl), publish, merge halves
  #pragma unroll
  for (int o = 1; o < 16; o <<= 1){
    #pragma unroll
    for (int m = 0; m < 4; ++m)
      #pragma unroll
      for (int j = 0; j < 4; ++j)
        accw[m][j] += __shfl_xor(accw[m][j], o);
    swl += __shfl_xor(swl, o);
  }
  if (r16 == 0){
    float* dst = mAcc + (ns * 2 + half) * 64;
    #pragma unroll
    for (int m = 0; m < 4; ++m)
      *(f32x4*)(dst + 16*m + 4*g) = accw[m];
    if (lane == 0) mSw[ns * 2 + half] = swl;
  }
  __syncthreads();
  if (tid < 256){
    const int n2 = tid >> 6, d = tid & 63;
    const float tot = mSw[n2 * 2] + mSw[n2 * 2 + 1];
    const float v = (mAcc[n2 * 128 + d] + mAcc[n2 * 128 + 64 + d]) / tot;
    out[(size_t)(blockIdx.x * 4 + n2) * 64 + d] = v;
  }
}

extern "C" void kernel_launch(void* const* d_in, const int* in_sizes, int n_in,
                              void* d_out, int out_size, void* d_ws, size_t ws_size,
                              hipStream_t stream){
  const int*   nodes = (const int*)  d_in[0];
  const int*   huv   = (const int*)  d_in[1];
  const int*   hr    = (const int*)  d_in[2];
  const float* u2e   = (const float*)d_in[3];
  const float* v2e   = (const float*)d_in[4];
  const float* r2e   = (const float*)d_in[5];
  const float* w1    = (const float*)d_in[6];
  const float* b1    = (const float*)d_in[7];
  const float* w2    = (const float*)d_in[8];
  const float* b2    = (const float*)d_in[9];
  const float* muw   = (const float*)d_in[10];
  const float* mub   = (const float*)d_in[11];
  const float* a1w   = (const float*)d_in[12];
  const float* a1b   = (const float*)d_in[13];
  const float* a2w   = (const float*)d_in[14];
  const float* a2b   = (const float*)d_in[15];
  const float* a3w   = (const float*)d_in[16];
  // d_in[17] = att3_b: constant logit offset -> cancels in softmax.

  const int N = in_sizes[0];            // 2048
  uint4* ws = (uint4*)d_ws;             // 74 KiB: frag table + r2e frags

  hipLaunchKernelGGL(prep_weights, dim3(74), dim3(64), 0, stream,
                     w1, w2, muw, a1w, a2w, r2e, ws);
  hipLaunchKernelGGL(uv_agg_main, dim3(N / 4), dim3(512), 79392, stream,
                     nodes, huv, hr, u2e, v2e,
                     b1, b2, mub, a1b, a2b, a3w,
                     (const uint4*)ws, (float*)d_out);
}